// Round 1
// baseline (473.487 us; speedup 1.0000x reference)
//
#include <hip/hip_runtime.h>

#define Bn 16
#define Cn 256
#define HWn 9216
#define Pn 64
#define HEADSn 4
#define Gn 2304
#define TSn 64
#define TILES_PER_B (HWn / TSn)   // 144

// ---------------- K1: x -> h(BN,ReLU) -> y (stored to d_out) + partial logits ----
__global__ __launch_bounds__(256, 2)
void k1_gemm_logits(const float* __restrict__ x,
                    const float* __restrict__ w1, const float* __restrict__ b1,
                    const float* __restrict__ gamma, const float* __restrict__ beta,
                    const float* __restrict__ mean, const float* __restrict__ var,
                    const float* __restrict__ w2, const float* __restrict__ b2,
                    const float* __restrict__ wm,
                    float* __restrict__ y, float* __restrict__ logits)
{
    __shared__ float xs[Cn][TSn];   // 64 KB
    __shared__ float hs[Pn][TSn];   // 16 KB

    const int bid  = blockIdx.x;
    const int b    = bid / TILES_PER_B;
    const int tile = bid % TILES_PER_B;
    const int s0   = tile * TSn;
    const int head = s0 / Gn;                 // 64-tiles never straddle heads (G/64=36)
    const int t    = threadIdx.x;
    const int lane = t & 63;
    const int wv   = __builtin_amdgcn_readfirstlane(t >> 6);  // wave id in SGPR

    // ---- stage x[b, :, s0:s0+64] into LDS (coalesced: one 256B row per wave/iter)
    {
        const float* xb = x + (size_t)b * Cn * HWn + s0;
        const int c0 = t >> 6, s = t & 63;
        #pragma unroll 8
        for (int c = c0; c < Cn; c += 4)
            xs[c][s] = xb[(size_t)c * HWn + s];
    }
    __syncthreads();

    // ---- GEMM1: wave wv computes h rows p in [16*wv, 16*wv+16), cols = lanes
    float acc[16];
    #pragma unroll
    for (int i = 0; i < 16; ++i) acc[i] = 0.f;
    const int p0 = wv * 16;
    #pragma unroll 4
    for (int c = 0; c < Cn; ++c) {
        const float xv = xs[c][lane];                 // stride-1 -> conflict-free
        #pragma unroll
        for (int i = 0; i < 16; ++i)                  // w1 addr is wave-uniform -> s_load
            acc[i] = fmaf(w1[(p0 + i) * Cn + c], xv, acc[i]);
    }
    #pragma unroll
    for (int i = 0; i < 16; ++i) {
        const int p = p0 + i;
        const float sc = gamma[p] * rsqrtf(var[p] + 1e-5f);
        const float bc = (b1[p] - mean[p]) * sc + beta[p];   // fold conv bias into BN
        const float h  = fmaf(acc[i], sc, bc);
        hs[p][lane] = h > 0.f ? h : 0.f;
    }
    __syncthreads();

    // ---- GEMM2: wave wv computes y rows c in [64*wv, 64*wv+64), 16 at a time
    const float wmv = wm[s0 + lane];        // wm flat over [HEADS*G] == spatial index s
    float* yb = y + (size_t)b * Cn * HWn + s0;
    float* lg = logits + (b * HEADSn + head) * Cn;
    #pragma unroll
    for (int cc = 0; cc < 4; ++cc) {
        float acc2[16];
        #pragma unroll
        for (int i = 0; i < 16; ++i) acc2[i] = 0.f;
        const int r0 = wv * 64 + cc * 16;
        #pragma unroll 4
        for (int k = 0; k < Pn; ++k) {
            const float hv = hs[k][lane];
            #pragma unroll
            for (int i = 0; i < 16; ++i)
                acc2[i] = fmaf(w2[(r0 + i) * Pn + k], hv, acc2[i]);
        }
        #pragma unroll
        for (int i = 0; i < 16; ++i) {
            const int r = r0 + i;
            const float yv = acc2[i] + b2[r];
            yb[(size_t)r * HWn + lane] = yv;          // coalesced 256B row store
            // partial logit for channel r: sum over this tile's 64 positions
            float ps = yv * wmv;
            #pragma unroll
            for (int off = 32; off; off >>= 1)
                ps += __shfl_xor(ps, off, 64);
            if (lane == 0) atomicAdd(&lg[r], ps);
        }
    }
}

// ---------------- K2: softmax over channels (bm dropped: constant over softmax axis)
__global__ __launch_bounds__(256)
void k2_softmax(const float* __restrict__ logits, float* __restrict__ mask)
{
    __shared__ float red[4];
    __shared__ float red2[4];
    const int bh = blockIdx.x;
    const int t  = threadIdx.x;
    const float lv = logits[bh * Cn + t];
    float m = lv;
    #pragma unroll
    for (int off = 32; off; off >>= 1) m = fmaxf(m, __shfl_xor(m, off, 64));
    if ((t & 63) == 0) red[t >> 6] = m;
    __syncthreads();
    m = fmaxf(fmaxf(red[0], red[1]), fmaxf(red[2], red[3]));
    const float ev = expf(lv - m);
    float s = ev;
    #pragma unroll
    for (int off = 32; off; off >>= 1) s += __shfl_xor(s, off, 64);
    if ((t & 63) == 0) red2[t >> 6] = s;
    __syncthreads();
    s = red2[0] + red2[1] + red2[2] + red2[3];
    mask[bh * Cn + t] = ev / s;
}

// ---------------- K3: ctx = y . mask (per position), out = x + ctx (in-place over y)
__global__ __launch_bounds__(256)
void k3_ctx_out(const float* __restrict__ x, const float* __restrict__ mask,
                float* __restrict__ yo)
{
    __shared__ float mk[Cn];
    __shared__ float part[4][TSn];
    __shared__ float ctx[TSn];

    const int bid  = blockIdx.x;
    const int b    = bid / TILES_PER_B;
    const int tile = bid % TILES_PER_B;
    const int s0   = tile * TSn;
    const int head = s0 / Gn;
    const int t    = threadIdx.x;
    const int lane = t & 63;
    const int wv   = t >> 6;

    mk[t] = mask[(b * HEADSn + head) * Cn + t];
    __syncthreads();

    float* yb = yo + (size_t)b * Cn * HWn + s0;
    float pc = 0.f;
    #pragma unroll 8
    for (int j = 0; j < 64; ++j) {
        const int c = wv * 64 + j;
        pc = fmaf(yb[(size_t)c * HWn + lane], mk[c], pc);   // coalesced reads of y
    }
    part[wv][lane] = pc;
    __syncthreads();
    if (t < TSn) ctx[t] = part[0][t] + part[1][t] + part[2][t] + part[3][t];
    __syncthreads();

    const float cv = ctx[lane];
    const float* xb = x + (size_t)b * Cn * HWn + s0;
    #pragma unroll 8
    for (int j = 0; j < 64; ++j) {
        const int c = j * 4 + wv;
        yb[(size_t)c * HWn + lane] = xb[(size_t)c * HWn + lane] + cv;  // overwrite y
    }
}

extern "C" void kernel_launch(void* const* d_in, const int* in_sizes, int n_in,
                              void* d_out, int out_size, void* d_ws, size_t ws_size,
                              hipStream_t stream)
{
    (void)in_sizes; (void)n_in; (void)out_size; (void)ws_size;
    const float* x     = (const float*)d_in[0];
    const float* w1    = (const float*)d_in[1];
    const float* b1    = (const float*)d_in[2];
    const float* gamma = (const float*)d_in[3];
    const float* beta  = (const float*)d_in[4];
    const float* mean  = (const float*)d_in[5];
    const float* var   = (const float*)d_in[6];
    const float* w2    = (const float*)d_in[7];
    const float* b2    = (const float*)d_in[8];
    const float* wm    = (const float*)d_in[9];
    // d_in[10] = bm: constant over softmax axis -> dropped

    float* out    = (float*)d_out;                 // doubles as y scratch
    float* logits = (float*)d_ws;                  // 64 KB
    float* mask   = logits + Bn * HEADSn * Cn;     // 64 KB

    hipMemsetAsync(logits, 0, Bn * HEADSn * Cn * sizeof(float), stream);

    dim3 blk(256);
    k1_gemm_logits<<<dim3(Bn * TILES_PER_B), blk, 0, stream>>>(
        x, w1, b1, gamma, beta, mean, var, w2, b2, wm, out, logits);
    k2_softmax<<<dim3(Bn * HEADSn), blk, 0, stream>>>(logits, mask);
    k3_ctx_out<<<dim3(Bn * TILES_PER_B), blk, 0, stream>>>(x, mask, out);
}

// Round 2
// 139.781 us; speedup vs baseline: 3.3873x; 3.3873x over previous
//
#include <hip/hip_runtime.h>

#define Bn 16
#define Cn 256
#define HWn 9216
#define Pn 64
#define HEADSn 4
#define Gn 2304
#define STILE 64                     // spatial positions per block (4 waves x 16)
#define NBLK (Bn * HWn / STILE)      // 2304

typedef float f32x4 __attribute__((ext_vector_type(4)));
typedef short short8 __attribute__((ext_vector_type(8)));

static __device__ __forceinline__ unsigned short f2bf(float f) {
    unsigned int b = __builtin_bit_cast(unsigned int, f);
    unsigned int r = b + 0x7FFFu + ((b >> 16) & 1u);   // RNE
    return (unsigned short)(r >> 16);
}

// ---------------- K0: fold BN params: sc[p], bc[p] ----------------
__global__ void k0_prep(const float* __restrict__ b1, const float* __restrict__ gamma,
                        const float* __restrict__ beta, const float* __restrict__ mean,
                        const float* __restrict__ var, float* __restrict__ scbc)
{
    int p = threadIdx.x;
    if (p < Pn) {
        float s = gamma[p] * rsqrtf(var[p] + 1e-5f);
        scbc[p] = s;
        scbc[Pn + p] = (b1[p] - mean[p]) * s + beta[p];
    }
}

// ------- K1/K3 shared GEMM1 pass. MODE 0: hm atomics. MODE 1: ctx + out. -------
template <int MODE>
__global__ __launch_bounds__(256)
void gemm_pass(const float* __restrict__ x, const float* __restrict__ w1,
               const float* __restrict__ scbc, const float* __restrict__ wm,
               float* __restrict__ hm,
               const float* __restrict__ wmix, const float* __restrict__ bmix,
               float* __restrict__ out)
{
    __shared__ short w1l[Pn * Cn];   // bf16 w1, XOR-swizzled, 32 KB

    const int bid  = blockIdx.x;
    const int b    = bid / (HWn / STILE);
    const int tile = bid % (HWn / STILE);
    const int s0   = tile * STILE;
    const int head = s0 / Gn;                  // 64-tiles never straddle heads
    const int t    = threadIdx.x;
    const int lane = t & 63;
    const int wv   = t >> 6;
    const int g    = lane >> 4;                // 16-lane group
    const int m16  = lane & 15;

    // ---- stage w1 -> LDS bf16, swizzled: idx ^= (row&7)<<3 (16B granules) ----
    #pragma unroll
    for (int i = 0; i < 8; ++i) {
        const int cid = i * 256 + t;           // 2048 chunks of 8 floats
        const int row = cid >> 5;
        const int kc  = (cid & 31) << 3;
        const float4 a = *reinterpret_cast<const float4*>(w1 + row * Cn + kc);
        const float4 c = *reinterpret_cast<const float4*>(w1 + row * Cn + kc + 4);
        short8 v;
        v[0] = (short)f2bf(a.x); v[1] = (short)f2bf(a.y);
        v[2] = (short)f2bf(a.z); v[3] = (short)f2bf(a.w);
        v[4] = (short)f2bf(c.x); v[5] = (short)f2bf(c.y);
        v[6] = (short)f2bf(c.z); v[7] = (short)f2bf(c.w);
        const int idx = (row * Cn + kc) ^ ((row & 7) << 3);
        *reinterpret_cast<short8*>(&w1l[idx]) = v;
    }
    __syncthreads();

    // ---- GEMM1: D[p][s] = sum_c w1[p][c] * x[c][s], bf16 MFMA 16x16x32 ----
    const int sl = s0 + wv * 16 + m16;                    // within-batch spatial idx
    const float* xb = x + (size_t)b * Cn * HWn + sl;
    f32x4 acc[4] = { {0,0,0,0}, {0,0,0,0}, {0,0,0,0}, {0,0,0,0} };
    float xkeep[64];

    #pragma unroll
    for (int ks = 0; ks < 8; ++ks) {
        const float* bp = xb + (size_t)(ks * 32 + g * 8) * HWn;
        float xf[8];
        #pragma unroll
        for (int j = 0; j < 8; ++j) xf[j] = bp[(size_t)j * HWn];
        short8 bf;
        #pragma unroll
        for (int j = 0; j < 8; ++j) bf[j] = (short)f2bf(xf[j]);
        if (MODE == 1) {
            #pragma unroll
            for (int j = 0; j < 8; ++j) xkeep[ks * 8 + j] = xf[j];
        }
        #pragma unroll
        for (int rt = 0; rt < 4; ++rt) {
            const int row = rt * 16 + m16;
            const int idx = (row * Cn + ks * 32 + g * 8) ^ ((row & 7) << 3);
            const short8 af = *reinterpret_cast<const short8*>(&w1l[idx]);
            acc[rt] = __builtin_amdgcn_mfma_f32_16x16x32_bf16(af, bf, acc[rt], 0, 0, 0);
        }
    }

    // ---- BN + ReLU (C/D layout: col=lane&15, row=(lane>>4)*4+reg) ----
    float h[4][4];
    #pragma unroll
    for (int rt = 0; rt < 4; ++rt) {
        #pragma unroll
        for (int r = 0; r < 4; ++r) {
            const int p = rt * 16 + g * 4 + r;
            const float hv = acc[rt][r] * scbc[p] + scbc[Pn + p];
            h[rt][r] = hv > 0.f ? hv : 0.f;
        }
    }

    const int bh = b * HEADSn + head;
    if (MODE == 0) {
        // hm[p] += sum_s h[p][s]*wm[s] over this wave's 16 columns
        const float wmv = wm[sl];
        #pragma unroll
        for (int rt = 0; rt < 4; ++rt) {
            #pragma unroll
            for (int r = 0; r < 4; ++r) {
                float v = h[rt][r] * wmv;
                v += __shfl_xor(v, 1); v += __shfl_xor(v, 2);
                v += __shfl_xor(v, 4); v += __shfl_xor(v, 8);
                if (m16 == 0)
                    atomicAdd(&hm[bh * Pn + rt * 16 + g * 4 + r], v);
            }
        }
    } else {
        // ctx[s] = sum_p wmix[p]*h[p][s] + bmix ; out = x + ctx
        const float* wmx = wmix + bh * Pn;
        float cp = 0.f;
        #pragma unroll
        for (int rt = 0; rt < 4; ++rt) {
            #pragma unroll
            for (int r = 0; r < 4; ++r)
                cp = fmaf(wmx[rt * 16 + g * 4 + r], h[rt][r], cp);
        }
        cp += __shfl_xor(cp, 16);
        cp += __shfl_xor(cp, 32);
        cp += bmix[bh];
        float* ob = out + (size_t)b * Cn * HWn + sl;
        #pragma unroll
        for (int ks = 0; ks < 8; ++ks) {
            #pragma unroll
            for (int j = 0; j < 8; ++j)
                ob[(size_t)(ks * 32 + g * 8 + j) * HWn] = xkeep[ks * 8 + j] + cp;
        }
    }
}

// ---------------- K2: logits -> softmax -> wmix/bmix (64 tiny blocks) ----------
__global__ __launch_bounds__(256)
void k2_mask(const float* __restrict__ hm, const float* __restrict__ w2,
             const float* __restrict__ b2, const float* __restrict__ wm,
             float* __restrict__ wmix, float* __restrict__ bmix)
{
    __shared__ float hms[Pn];
    __shared__ float masks[Cn];
    __shared__ float red[4];
    __shared__ float part[4][Pn];

    const int bh = blockIdx.x;
    const int head = bh & (HEADSn - 1);
    const int t = threadIdx.x;
    const int l = t & 63;
    const int wv = t >> 6;

    if (t < Pn) hms[t] = hm[bh * Pn + t];

    // wmsum over this head's group
    float wsum = 0.f;
    for (int i = t; i < Gn; i += 256) wsum += wm[head * Gn + i];
    #pragma unroll
    for (int d = 1; d < 64; d <<= 1) wsum += __shfl_xor(wsum, d);
    if (l == 0) red[wv] = wsum;
    __syncthreads();
    wsum = red[0] + red[1] + red[2] + red[3];

    // logits[c] = sum_k w2[c,k]*hm[k] + b2[c]*wsum
    float lg = 0.f;
    #pragma unroll
    for (int k = 0; k < Pn; ++k) lg = fmaf(w2[t * Pn + k], hms[k], lg);
    lg = fmaf(b2[t], wsum, lg);

    // softmax over 256 channels
    float mx = lg;
    #pragma unroll
    for (int d = 1; d < 64; d <<= 1) mx = fmaxf(mx, __shfl_xor(mx, d));
    __syncthreads();
    if (l == 0) red[wv] = mx;
    __syncthreads();
    mx = fmaxf(fmaxf(red[0], red[1]), fmaxf(red[2], red[3]));
    const float ev = __expf(lg - mx);
    float sm = ev;
    #pragma unroll
    for (int d = 1; d < 64; d <<= 1) sm += __shfl_xor(sm, d);
    __syncthreads();
    if (l == 0) red[wv] = sm;
    __syncthreads();
    sm = red[0] + red[1] + red[2] + red[3];
    masks[t] = ev / sm;
    __syncthreads();

    // wmix[k] = sum_c mask[c]*w2[c,k]
    {
        const int k = t & (Pn - 1);
        const int q = t >> 6;
        float wp = 0.f;
        #pragma unroll
        for (int i = 0; i < 64; ++i) {
            const int c = q * 64 + i;
            wp = fmaf(masks[c], w2[c * Pn + k], wp);
        }
        part[q][k] = wp;
    }
    __syncthreads();
    if (t < Pn) wmix[bh * Pn + t] = part[0][t] + part[1][t] + part[2][t] + part[3][t];

    // bmix = sum_c mask[c]*b2[c]
    float bp = masks[t] * b2[t];
    #pragma unroll
    for (int d = 1; d < 64; d <<= 1) bp += __shfl_xor(bp, d);
    __syncthreads();
    if (l == 0) red[wv] = bp;
    __syncthreads();
    if (t == 0) bmix[bh] = red[0] + red[1] + red[2] + red[3];
}

extern "C" void kernel_launch(void* const* d_in, const int* in_sizes, int n_in,
                              void* d_out, int out_size, void* d_ws, size_t ws_size,
                              hipStream_t stream)
{
    (void)in_sizes; (void)n_in; (void)out_size; (void)ws_size;
    const float* x     = (const float*)d_in[0];
    const float* w1    = (const float*)d_in[1];
    const float* b1    = (const float*)d_in[2];
    const float* gamma = (const float*)d_in[3];
    const float* beta  = (const float*)d_in[4];
    const float* mean  = (const float*)d_in[5];
    const float* var   = (const float*)d_in[6];
    const float* w2    = (const float*)d_in[7];
    const float* b2    = (const float*)d_in[8];
    const float* wm    = (const float*)d_in[9];
    // d_in[10] = bm: constant over softmax axis -> dropped

    float* out  = (float*)d_out;
    float* wsf  = (float*)d_ws;
    float* hm   = wsf;                       // [64*64]
    float* wmix = wsf + Bn * HEADSn * Pn;    // [64*64]
    float* bmix = wsf + 2 * Bn * HEADSn * Pn;// [64]
    float* scbc = bmix + 64;                 // [128]

    hipMemsetAsync(hm, 0, Bn * HEADSn * Pn * sizeof(float), stream);
    k0_prep<<<dim3(1), dim3(64), 0, stream>>>(b1, gamma, beta, mean, var, scbc);
    gemm_pass<0><<<dim3(NBLK), dim3(256), 0, stream>>>(x, w1, scbc, wm, hm, nullptr, nullptr, nullptr);
    k2_mask<<<dim3(Bn * HEADSn), dim3(256), 0, stream>>>(hm, w2, b2, wm, wmix, bmix);
    gemm_pass<1><<<dim3(NBLK), dim3(256), 0, stream>>>(x, w1, scbc, wm, nullptr, wmix, bmix, out);
}